// Round 17
// baseline (583.870 us; speedup 1.0000x reference)
//
#include <hip/hip_runtime.h>

#define S_LEN 2048
#define DM    1024
#define NH    16
#define DH    64
#define BATCH 2
#define S2    ((size_t)S_LEN * S_LEN)
#define CTXSZ ((size_t)BATCH * S_LEN * DM)

typedef _Float16 half_t;
typedef _Float16 f16x8 __attribute__((ext_vector_type(8)));
typedef float    f32x4 __attribute__((ext_vector_type(4)));

// =====================================================================
// global->LDS direct (16B/lane). LDS dest wave-linear; XOR swizzle on the
// per-lane GLOBAL address (both-sides-or-neither), reads use the same XOR.
// =====================================================================
__device__ __forceinline__ void gll16(const void* g, void* l) {
  __builtin_amdgcn_global_load_lds(
      (const __attribute__((address_space(1))) void*)g,
      (__attribute__((address_space(3))) void*)l, 16, 0, 0);
}

// 256-thread version (used by gemm_k): 128 rows x 64 f16
__device__ __forceinline__ void stage_gll(half_t* lds, const half_t* src, int stride) {
  const int t = threadIdx.x, w = t >> 6, lane = t & 63;
  const int c1 = lane & 7, r8 = lane >> 3;
#pragma unroll
  for (int it = 0; it < 4; ++it) {
    int r = w * 32 + it * 8 + r8;
    const half_t* g = src + (size_t)r * stride + ((c1 ^ r8) << 3);
    gll16(g, lds + (size_t)w * 2048 + it * 512);
  }
}

// per-wave 32 rows x 128 cols over K=64 (4-wave kernels)
__device__ __forceinline__ void mfma_block(const half_t* At, const half_t* Bt,
                                           int w, int lane, f32x4 acc[2][8]) {
  const int grp = lane >> 4, li = lane & 15;
#pragma unroll
  for (int ks = 0; ks < 2; ++ks) {
    const int chunk = ks * 4 + grp;
    f16x8 a[2], b[8];
#pragma unroll
    for (int fr = 0; fr < 2; ++fr) {
      int r = w * 32 + fr * 16 + li;
      a[fr] = *(const f16x8*)&At[(size_t)(r * 8 + (chunk ^ (r & 7))) * 8];
    }
#pragma unroll
    for (int fc = 0; fc < 8; ++fc) {
      int r = fc * 16 + li;
      b[fc] = *(const f16x8*)&Bt[(size_t)(r * 8 + (chunk ^ (r & 7))) * 8];
    }
#pragma unroll
    for (int fr = 0; fr < 2; ++fr)
#pragma unroll
      for (int fc = 0; fc < 8; ++fc)
        acc[fr][fc] = __builtin_amdgcn_mfma_f32_16x16x32_f16(a[fr], b[fc], acc[fr][fc], 0, 0, 0);
  }
}

// =====================================================================
// PREP (merged): blocks [0,8192): activations f32->f16 (+zbuf init);
//                blocks [8192,9472): weight convert+transpose (5 mats).
// =====================================================================
struct PArgs {
  const float* asrc[4]; half_t* adst[4];
  const float* wsrc[5]; half_t* wdst[5];
};

__global__ __launch_bounds__(256) void prep(PArgs pa, half_t* zbuf) {
  __shared__ float T[64][65];
  const int bx = blockIdx.x, t = threadIdx.x;
  if (bx < 8192) {
    if (bx == 0 && t < 8) {
      float4 z = {0.f, 0.f, 0.f, 0.f};
      ((float4*)zbuf)[t] = z;
    }
    const int mat = bx >> 11, blk = bx & 2047;
    const float* s = pa.asrc[mat];
    half_t* d = pa.adst[mat];
    size_t i = ((size_t)blk * 256 + t) * 8;
    float4 v0 = *(const float4*)(s + i), v1 = *(const float4*)(s + i + 4);
    f16x8 h;
    h[0]=(half_t)v0.x; h[1]=(half_t)v0.y; h[2]=(half_t)v0.z; h[3]=(half_t)v0.w;
    h[4]=(half_t)v1.x; h[5]=(half_t)v1.y; h[6]=(half_t)v1.z; h[7]=(half_t)v1.w;
    *(f16x8*)(d + i) = h;
  } else {
    const int idx = bx - 8192;          // 0..1279
    const int z = idx >> 8, rem = idx & 255;
    const int k0 = (rem & 15) * 64, n0 = (rem >> 4) * 64;
    const float* W = pa.wsrc[z];
    half_t* D = pa.wdst[z];
#pragma unroll
    for (int it = 0; it < 4; ++it) {
      int id2 = t + it * 256; int r = id2 >> 4, c4 = (id2 & 15) * 4;
      float4 v = *(const float4*)(W + (size_t)(k0 + r) * DM + n0 + c4);
      T[r][c4] = v.x; T[r][c4 + 1] = v.y; T[r][c4 + 2] = v.z; T[r][c4 + 3] = v.w;
    }
    __syncthreads();
#pragma unroll
    for (int it = 0; it < 2; ++it) {
      int id2 = t + it * 256; int n = id2 >> 3, kc = (id2 & 7) * 8;
      f16x8 o;
#pragma unroll
      for (int e = 0; e < 8; ++e) o[e] = (half_t)T[kc + e][n];
      *(f16x8*)&D[(size_t)(n0 + n) * DM + k0 + kc] = o;
    }
  }
}

// =====================================================================
// GEMM: C[M,1024] = A[M,1024](f16) @ Wt[n][k]^T ; z-indexed operand sets.
// Grid must be (8, 32, gz). XCD swizzle: each (z,m0) group's 8 n-blocks
// land on ONE XCD (kept: R10 FETCH evidence, 135 MB vs 42 ideal).
// =====================================================================
struct GArgs {
  const half_t* A[4];  const half_t* Bt[4];
  const float* ba[4]; const float* bu[4]; const float* bv[4];
  half_t* oa[4]; half_t* ob[4]; float* of[4];
};

template<bool F32OUT>
__global__ __launch_bounds__(256) void gemm_k(GArgs g, int K) {
  __shared__ __align__(16) half_t At[128 * 64];
  __shared__ __align__(16) half_t Bt[128 * 64];
  // --- XCD-aware decode (bijective; nwg = 8*32*gz, divisible by 64) ---
  const int lin = blockIdx.x + 8 * (blockIdx.y + 32 * blockIdx.z);
  const int nwg = 8 * 32 * gridDim.z;
  const int xcd = lin & 7, tt = lin >> 3;
  const int grpid = xcd * (nwg >> 6) + (tt >> 3);  // (z,m0) group
  const int n0 = (tt & 7) * 128;
  const int z = grpid >> 5;
  const int m0 = (grpid & 31) * 128;

  const half_t* A = g.A[z];
  const half_t* B = g.Bt[z];
  const int t = threadIdx.x, w = t >> 6, lane = t & 63;
  const f32x4 zf = {0.f, 0.f, 0.f, 0.f};
  f32x4 acc[2][8];
#pragma unroll
  for (int i = 0; i < 2; ++i)
#pragma unroll
    for (int j = 0; j < 8; ++j) acc[i][j] = zf;

  for (int k0 = 0; k0 < K; k0 += 64) {
    stage_gll(At, A + (size_t)m0 * K + k0, K);
    stage_gll(Bt, B + (size_t)n0 * K + k0, K);
    __syncthreads();
    mfma_block(At, Bt, w, lane, acc);
    __syncthreads();
  }
  const int grp = lane >> 4, li = lane & 15;
#pragma unroll
  for (int fr = 0; fr < 2; ++fr)
#pragma unroll
    for (int fc = 0; fc < 8; ++fc)
#pragma unroll
      for (int r = 0; r < 4; ++r) {
        int row = m0 + w * 32 + fr * 16 + grp * 4 + r;
        int col = n0 + fc * 16 + li;
        float v = acc[fr][fc][r];
        if (g.ba[z]) v += g.ba[z][col];
        if constexpr (F32OUT) {
          g.of[z][(size_t)row * DM + col] = v;
        } else {
          float v1 = v + (g.bu[z] ? g.bu[z][col] : 0.f);
          g.oa[z][(size_t)row * DM + col] = (half_t)v1;
          if (g.ob[z]) g.ob[z][(size_t)row * DM + col] = (half_t)(v + g.bv[z][col]);
        }
      }
}

// =====================================================================
// V transpose per head: vp[b*S+s][h*64+d] -> vT[bh][d][s]  (f16)
// =====================================================================
__global__ __launch_bounds__(256) void vtrans(const half_t* vp, half_t* vT) {
  __shared__ half_t T[64][72];
  const int s0 = blockIdx.x * 64, h = blockIdx.y, b = blockIdx.z;
  const int t = threadIdx.x;
#pragma unroll
  for (int it = 0; it < 2; ++it) {
    int idx = t + it * 256; int s = idx >> 3, c = idx & 7;
    uint4 v = *(const uint4*)(vp + ((size_t)(b * S_LEN + s0 + s)) * DM + h * DH + c * 8);
    *(uint4*)&T[s][c * 8] = v;
  }
  __syncthreads();
  half_t* dst = vT + ((size_t)(b * NH + h)) * DH * S_LEN;
#pragma unroll
  for (int it = 0; it < 2; ++it) {
    int idx = t + it * 256; int d = idx >> 3, sc = (idx & 7) * 8;
    f16x8 o;
#pragma unroll
    for (int e = 0; e < 8; ++e) o[e] = T[sc + e][d];
    *(f16x8*)&dst[(size_t)d * S_LEN + s0 + sc] = o;
  }
}

// =====================================================================
// FUSED scores v3: natural grid; writer-side shear with strength-reduced
// addressing: addr(rM) = rM*133 + C, valid window [lo,hi].
// Combine loop: hoisted per-row bases. LDS 50,176 B -> 3 blocks/CU.
// =====================================================================
template<typename ST>
__global__ __launch_bounds__(512, 6) void score_fused(
    const half_t* __restrict__ qu_, const half_t* __restrict__ qv_,
    const half_t* __restrict__ kp_, const half_t* __restrict__ pp_,
    const half_t* __restrict__ zbuf, ST* __restrict__ sc, float* __restrict__ part)
{
  __shared__ __align__(16) half_t MsR[16896];   // 33,792 B
  __shared__ __align__(16) half_t QV[128 * 64]; // 16 KB
  half_t* QU = MsR;                             // phase 1
  half_t* Kt = MsR + 8192;
  half_t* Ms = MsR;                             // phase 2: [128][132] f16

  const int bh = blockIdx.z, b = bh >> 4, h = bh & 15;
  const int kt = blockIdx.x, qt = blockIdx.y;
  const int i0 = qt * 128, k0 = kt * 128;
  const int base = 1920 + k0 - i0;              // in [0,3840]
  const int t = threadIdx.x, w = t >> 6, lane = t & 63;
  const int grp = lane >> 4, li = lane & 15;

  // ---- stage QU, Kt, QV (128x64 each; swizzled global src) ----
  {
    const half_t* srcA = qu_ + ((size_t)(b * S_LEN + i0)) * DM + h * DH;
    const half_t* srcB = kp_ + ((size_t)(b * S_LEN + k0)) * DM + h * DH;
    const half_t* srcQ = qv_ + ((size_t)(b * S_LEN + i0)) * DM + h * DH;
#pragma unroll
    for (int p = 0; p < 2; ++p) {
      int cidx = t + p * 512; int r = cidx >> 3, c = cidx & 7;
      size_t off = (size_t)r * DM + ((c ^ (r & 7)) << 3);
      gll16(srcA + off, QU + (size_t)cidx * 8);
      gll16(srcB + off, Kt + (size_t)cidx * 8);
      gll16(srcQ + off, QV + (size_t)cidx * 8);
    }
  }

  // ---- band B-fragments: global -> registers (rows jv(e), zero row) ----
  const int e0 = w * 16 + li, e1 = (w + 8) * 16 + li;
  const int dlt0 = (base + e0 >= S_LEN + 1) ? 1 : 0;
  const int dlt1 = (base + e1 >= S_LEN + 1) ? 1 : 0;
  f16x8 bm[2][2];
#pragma unroll
  for (int eci = 0; eci < 2; ++eci) {
    int e_row = eci ? e1 : e0;
    int jv = base + e_row; if (jv >= S_LEN + 1) jv -= (S_LEN + 1);
    const half_t* srcp = (jv == S_LEN) ? zbuf
        : pp_ + ((size_t)(b * S_LEN + jv)) * DM + h * DH;
#pragma unroll
    for (int kk = 0; kk < 2; ++kk)
      bm[kk][eci] = *(const f16x8*)(srcp + (kk * 4 + grp) * 8);
  }
  __syncthreads();

  // ---- content MFMA: wave w owns q rows [w*16, w*16+16) ----
  const f32x4 zf = {0.f, 0.f, 0.f, 0.f};
  f32x4 acc_c[8];
#pragma unroll
  for (int j = 0; j < 8; ++j) acc_c[j] = zf;
#pragma unroll
  for (int kk = 0; kk < 2; ++kk) {
    const int chunk = kk * 4 + grp;
    int ra = w * 16 + li;
    f16x8 a = *(const f16x8*)&QU[(size_t)(ra * 8 + (chunk ^ (ra & 7))) * 8];
#pragma unroll
    for (int fc = 0; fc < 8; ++fc) {
      int rb = fc * 16 + li;
      f16x8 bf = *(const f16x8*)&Kt[(size_t)(rb * 8 + (chunk ^ (rb & 7))) * 8];
      acc_c[fc] = __builtin_amdgcn_mfma_f32_16x16x32_f16(a, bf, acc_c[fc], 0, 0, 0);
    }
  }
  __syncthreads();   // QU/Kt reads done; region now writable as Ms

  // ---- band MFMA rf=0..7, writer-side shear (strength-reduced) ----
  const int C0 = e0 - 127 - 133 * dlt0;
  const int C1 = e1 - 127 - 133 * dlt1;
  int lo0 = 127 + dlt0 - e0; if (lo0 < dlt0) lo0 = dlt0;
  int hi0 = 254 + dlt0 - e0; if (hi0 > 127) hi0 = 127;
  int lo1 = 127 + dlt1 - e1; if (lo1 < dlt1) lo1 = dlt1;
  int hi1 = 254 + dlt1 - e1; if (hi1 > 127) hi1 = 127;

  for (int rf = 0; rf < 8; ++rf) {
    f32x4 am[2] = {zf, zf};
#pragma unroll
    for (int kk = 0; kk < 2; ++kk) {
      int ra = rf * 16 + li;
      f16x8 a = *(const f16x8*)&QV[(size_t)(ra * 8 + ((kk * 4 + grp) ^ (ra & 7))) * 8];
      am[0] = __builtin_amdgcn_mfma_f32_16x16x32_f16(a, bm[kk][0], am[0], 0, 0, 0);
      am[1] = __builtin_amdgcn_mfma_f32_16x16x32_f16(a, bm[kk][1], am[1], 0, 0, 0);
    }
    const int rMb = rf * 16 + grp * 4;
    {
      int addr = rMb * 133 + C0;
#pragma unroll
      for (int r = 0; r < 4; ++r) {
        int rM = rMb + r;
        if (rM >= lo0 && rM <= hi0) Ms[addr + 133 * r] = (half_t)am[0][r];
      }
    }
    {
      int addr = rMb * 133 + C1;
#pragma unroll
      for (int r = 0; r < 4; ++r) {
        int rM = rMb + r;
        if (rM >= lo1 && rM <= hi1) Ms[addr + 133 * r] = (half_t)am[1][r];
      }
    }
  }

  // ---- 9th row-frag (rM=128 -> q=127, needs dlt(e)==1, e<128) ----
  {
    f16x8 aq0, aq1;                              // lazy load: short live range
    {
      int r128 = i0 + 128; if (r128 > S_LEN - 1) r128 = S_LEN - 1;
      const half_t* q128p = qv_ + ((size_t)(b * S_LEN + r128)) * DM + h * DH;
      aq0 = *(const f16x8*)(q128p + (0 * 4 + grp) * 8);
      aq1 = *(const f16x8*)(q128p + (1 * 4 + grp) * 8);
    }
    f32x4 am0 = zf;
    am0 = __builtin_amdgcn_mfma_f32_16x16x32_f16(aq0, bm[0][0], am0, 0, 0, 0);
    am0 = __builtin_amdgcn_mfma_f32_16x16x32_f16(aq1, bm[1][0], am0, 0, 0, 0);
    if (grp == 0 && dlt0 == 1)                   // e0 < 128 always (w<8)
      Ms[127 * 132 + e0] = (half_t)am0[0];
  }
  __syncthreads();

  // ---- combine: hoisted bases; s=(content+Ms)/32; exp; write; partials ----
  ST* sb = sc + (size_t)bh * S2;
  const int qb = w * 16 + grp * 4;
  const half_t* MsB = Ms + qb * 132 + li;
  ST* sbB = sb + (size_t)(i0 + qb) * S_LEN + k0 + li;
  float lsum[4];
#pragma unroll
  for (int rr = 0; rr < 4; ++rr) {
    const half_t* mrow = MsB + rr * 132;
    ST* srow = sbB + (size_t)rr * S_LEN;
    float acc = 0.f;
#pragma unroll
    for (int fc = 0; fc < 8; ++fc) {
      float mval = (float)mrow[fc * 16];
      float s = (acc_c[fc][rr] + mval) * 0.03125f;
      float ev = __expf(s);
      srow[fc * 16] = (ST)ev;
      acc += ev;
    }
    lsum[rr] = acc;
  }
#pragma unroll
  for (int rr = 0; rr < 4; ++rr) {
    float v = lsum[rr];
#pragma unroll
    for (int d = 1; d < 16; d <<= 1) v += __shfl_xor(v, d);
    if (li == 0)
      part[((size_t)bh * S_LEN + i0 + qb + rr) * 16 + kt] = v;
  }
}

// =====================================================================
// Pass 3 v4 (BARRIER-FREE k-loop): combine sumexp partials -> 1/L (regs);
// stream exp tiles (plain loads), scale, plain f32 attn store, and read
// V B-fragments DIRECTLY FROM GLOBAL vT (L2-resident: 256 KB/bh shared by
// 16 blocks). No LDS V staging -> no __syncthreads in the loop -> stores
// never gate the MFMA pipeline (R16 showed vmcnt(0) drains at each kt
// barrier serialized the kernel: 327 us, MfmaUtil 2%).
// =====================================================================
template<typename ST>
__global__ __launch_bounds__(256) void av_attn(const ST* sc, const half_t* vT, const float* part,
                                               float* attn, half_t* ctx) {
  __shared__ float Ls[128];
  const int bh = blockIdx.y, b = bh >> 4, h = bh & 15;
  const int q0 = blockIdx.x * 128;
  const int t = threadIdx.x;
  if (t < 128) {
    const float* pp = part + ((size_t)bh * S_LEN + q0 + t) * 16;
    float L = 0.f;
#pragma unroll
    for (int k = 0; k < 16; ++k) L += pp[k];
    Ls[t] = 1.f / L;
  }
  __syncthreads();
  const ST* sb = sc + (size_t)bh * S2;
  float* ab = attn + (size_t)bh * S2;
  const half_t* vb = vT + (size_t)bh * (DH * S_LEN);
  const int w = t >> 6, lane = t & 63, grp = lane >> 4, li = lane & 15;
  const float rL0 = Ls[w * 32 + li];
  const float rL1 = Ls[w * 32 + 16 + li];
  const f32x4 zf = {0.f, 0.f, 0.f, 0.f};
  f32x4 acc[2][4];
#pragma unroll
  for (int i = 0; i < 2; ++i)
#pragma unroll
    for (int j = 0; j < 4; ++j) acc[i][j] = zf;

  for (int kt = 0; kt < 16; ++kt) {
#pragma unroll
    for (int ks = 0; ks < 4; ++ks) {
      const int col = kt * 128 + ks * 32 + grp * 8;
      f16x8 pa[2];
#pragma unroll
      for (int fr = 0; fr < 2; ++fr) {
        const int row = q0 + w * 32 + fr * 16 + li;
        const float rL = fr ? rL1 : rL0;
        float sv[8];
        if constexpr (sizeof(ST) == 2) {
          f16x8 v = *(const f16x8*)&sb[(size_t)row * S_LEN + col];
#pragma unroll
          for (int e = 0; e < 8; ++e) sv[e] = (float)v[e] * rL;
        } else {
          const f32x4* sp = (const f32x4*)&sb[(size_t)row * S_LEN + col];
          f32x4 a = sp[0], bq = sp[1];
#pragma unroll
          for (int e = 0; e < 4; ++e) { sv[e] = a[e] * rL; sv[4 + e] = bq[e] * rL; }
        }
        f32x4* dst = (f32x4*)&ab[(size_t)row * S_LEN + col];
        f32x4 w0 = {sv[0], sv[1], sv[2], sv[3]};
        f32x4 w1 = {sv[4], sv[5], sv[6], sv[7]};
        dst[0] = w0; dst[1] = w1;
        f16x8 ph;
#pragma unroll
        for (int e = 0; e < 8; ++e) ph[e] = (half_t)sv[e];
        pa[fr] = ph;
      }
      f16x8 bf[4];
#pragma unroll
      for (int fc = 0; fc < 4; ++fc)
        bf[fc] = *(const f16x8*)&vb[(size_t)(fc * 16 + li) * S_LEN + col];
#pragma unroll
      for (int fr = 0; fr < 2; ++fr)
#pragma unroll
        for (int fc = 0; fc < 4; ++fc)
          acc[fr][fc] = __builtin_amdgcn_mfma_f32_16x16x32_f16(pa[fr], bf[fc], acc[fr][fc], 0, 0, 0);
    }
  }
#pragma unroll
  for (int fr = 0; fr < 2; ++fr)
#pragma unroll
    for (int fc = 0; fc < 4; ++fc)
#pragma unroll
      for (int r = 0; r < 4; ++r) {
        int q = q0 + w * 32 + fr * 16 + grp * 4 + r;
        int d = fc * 16 + li;
        ctx[((size_t)(b * S_LEN + q)) * DM + h * DH + d] = (half_t)acc[fr][fc][r];
      }
}

// =====================================================================
extern "C" void kernel_launch(void* const* d_in, const int* in_sizes, int n_in,
                              void* d_out, int out_size, void* d_ws, size_t ws_size,
                              hipStream_t stream) {
  (void)in_sizes; (void)n_in; (void)out_size;

  const float* query  = (const float*)d_in[0];
  const float* key    = (const float*)d_in[1];
  const float* value  = (const float*)d_in[2];
  const float* pos    = (const float*)d_in[3];
  const float* Wq     = (const float*)d_in[4];
  const float* bq     = (const float*)d_in[5];
  const float* Wk     = (const float*)d_in[6];
  const float* bk     = (const float*)d_in[7];
  const float* Wv     = (const float*)d_in[8];
  const float* bv     = (const float*)d_in[9];
  const float* Wpos   = (const float*)d_in[10];
  const float* u_bias = (const float*)d_in[11];  // [16,64] == flat [1024]
  const float* v_bias = (const float*)d_in[12];
  const float* Wout   = (const float*)d_in[13];
  const float* bout   = (const float*)d_in[14];

  float* out  = (float*)d_out;
  float* attn = out + (size_t)BATCH * S_LEN * DM;

  char* ws = (char*)d_ws;
  half_t* Wt   = (half_t*)(ws);                 // 5 x 1024x1024 f16 = 10,485,760 B
  half_t* Af16 = (half_t*)(ws + 10485760);      // 4 x 8,388,608 B (dead after proj)
  float*  part = (float*)(ws + 10485760);       // 4 MB, aliases Af16[0] post-proj
  half_t* qu   = (half_t*)(ws + 44040192);
  half_t* qv   = (half_t*)(ws + 52428800);
  half_t* kp   = (half_t*)(ws + 60817408);
  half_t* pp   = (half_t*)(ws + 69206016);
  half_t* vp   = (half_t*)(ws + 77594624);
  half_t* vT   = (half_t*)(ws + 85983232);
  half_t* ctx  = (half_t*)(ws + 77594624);      // alias vp (dead after vtrans)
  half_t* zbuf = (half_t*)(ws + 94371840);      // 128 B zero row
  half_t* scH  = (half_t*)(ws + 94375936);      // 268,435,456 B if it fits
  const bool fast = ws_size >= (size_t)94375936 + (size_t)BATCH * NH * S2 * 2;

  dim3 blk(256);

  // 0. prep: activations -> f16 + zbuf init + weights -> f16 transposed
  PArgs pa;
  pa.asrc[0] = query; pa.asrc[1] = key; pa.asrc[2] = value; pa.asrc[3] = pos;
  for (int i = 0; i < 4; ++i) pa.adst[i] = Af16 + (size_t)i * CTXSZ;
  pa.wsrc[0] = Wq; pa.wsrc[1] = Wk; pa.wsrc[2] = Wv; pa.wsrc[3] = Wpos; pa.wsrc[4] = Wout;
  for (int i = 0; i < 5; ++i) pa.wdst[i] = Wt + (size_t)i * DM * DM;
  prep<<<dim3(8192 + 1280), blk, 0, stream>>>(pa, zbuf);

  // 1. projections (q dual-output with u/v biases, k, v, p) in one launch
  GArgs ga{};
  for (int i = 0; i < 4; ++i) {
    ga.A[i]  = Af16 + (size_t)i * CTXSZ;
    ga.Bt[i] = Wt + (size_t)i * DM * DM;
  }
  ga.ba[0] = bq; ga.ba[1] = bk; ga.ba[2] = bv; ga.ba[3] = nullptr;
  ga.bu[0] = u_bias; ga.bv[0] = v_bias;
  ga.oa[0] = qu; ga.oa[1] = kp; ga.oa[2] = vp; ga.oa[3] = pp;
  ga.ob[0] = qv;
  gemm_k<false><<<dim3(8, 32, 4), blk, 0, stream>>>(ga, DM);

  // 2. V -> per-head transposed [bh][d][s]
  vtrans<<<dim3(32, 16, 2), blk, 0, stream>>>(vp, vT);

  // 3. fused scores (writer-shear, strength-reduced), 4. attn + PV (barrier-free)
  dim3 g_sc(16, 16, 32);
  dim3 blk5(512);
  if (fast) {
    score_fused<half_t><<<g_sc, blk5, 0, stream>>>(qu, qv, kp, pp, zbuf, scH, part);
    av_attn<half_t><<<dim3(16, 32), blk, 0, stream>>>(scH, vT, part, attn, ctx);
  } else {
    float* scF = attn;  // f32 exp-scores in-place in the attn output region
    score_fused<float><<<g_sc, blk5, 0, stream>>>(qu, qv, kp, pp, zbuf, scF, part);
    av_attn<float><<<dim3(16, 32), blk, 0, stream>>>(scF, vT, part, attn, ctx);
  }

  // 5. out = ctx @ Wout^T + bout  (f32 output)
  GArgs go{};
  go.A[0] = ctx; go.Bt[0] = Wt + (size_t)4 * DM * DM;
  go.ba[0] = bout; go.of[0] = out;
  gemm_k<true><<<dim3(8, 32, 1), blk, 0, stream>>>(go, DM);
}

// Round 18
// 493.425 us; speedup vs baseline: 1.1833x; 1.1833x over previous
//
#include <hip/hip_runtime.h>

#define S_LEN 2048
#define DM    1024
#define NH    16
#define DH    64
#define BATCH 2
#define S2    ((size_t)S_LEN * S_LEN)
#define CTXSZ ((size_t)BATCH * S_LEN * DM)

typedef _Float16 half_t;
typedef _Float16 f16x8 __attribute__((ext_vector_type(8)));
typedef float    f32x4 __attribute__((ext_vector_type(4)));

// =====================================================================
// global->LDS direct (16B/lane). LDS dest wave-linear; XOR swizzle on the
// per-lane GLOBAL address (both-sides-or-neither), reads use the same XOR.
// =====================================================================
__device__ __forceinline__ void gll16(const void* g, void* l) {
  __builtin_amdgcn_global_load_lds(
      (const __attribute__((address_space(1))) void*)g,
      (__attribute__((address_space(3))) void*)l, 16, 0, 0);
}

// 256-thread version (used by gemm_k): 128 rows x 64 f16
__device__ __forceinline__ void stage_gll(half_t* lds, const half_t* src, int stride) {
  const int t = threadIdx.x, w = t >> 6, lane = t & 63;
  const int c1 = lane & 7, r8 = lane >> 3;
#pragma unroll
  for (int it = 0; it < 4; ++it) {
    int r = w * 32 + it * 8 + r8;
    const half_t* g = src + (size_t)r * stride + ((c1 ^ r8) << 3);
    gll16(g, lds + (size_t)w * 2048 + it * 512);
  }
}

// per-wave 32 rows x 128 cols over K=64 (4-wave kernels)
__device__ __forceinline__ void mfma_block(const half_t* At, const half_t* Bt,
                                           int w, int lane, f32x4 acc[2][8]) {
  const int grp = lane >> 4, li = lane & 15;
#pragma unroll
  for (int ks = 0; ks < 2; ++ks) {
    const int chunk = ks * 4 + grp;
    f16x8 a[2], b[8];
#pragma unroll
    for (int fr = 0; fr < 2; ++fr) {
      int r = w * 32 + fr * 16 + li;
      a[fr] = *(const f16x8*)&At[(size_t)(r * 8 + (chunk ^ (r & 7))) * 8];
    }
#pragma unroll
    for (int fc = 0; fc < 8; ++fc) {
      int r = fc * 16 + li;
      b[fc] = *(const f16x8*)&Bt[(size_t)(r * 8 + (chunk ^ (r & 7))) * 8];
    }
#pragma unroll
    for (int fr = 0; fr < 2; ++fr)
#pragma unroll
      for (int fc = 0; fc < 8; ++fc)
        acc[fr][fc] = __builtin_amdgcn_mfma_f32_16x16x32_f16(a[fr], b[fc], acc[fr][fc], 0, 0, 0);
  }
}

// =====================================================================
// PREP (merged): blocks [0,8192): activations f32->f16 (+zbuf init);
//                blocks [8192,9472): weight convert+transpose (5 mats).
// =====================================================================
struct PArgs {
  const float* asrc[4]; half_t* adst[4];
  const float* wsrc[5]; half_t* wdst[5];
};

__global__ __launch_bounds__(256) void prep(PArgs pa, half_t* zbuf) {
  __shared__ float T[64][65];
  const int bx = blockIdx.x, t = threadIdx.x;
  if (bx < 8192) {
    if (bx == 0 && t < 8) {
      float4 z = {0.f, 0.f, 0.f, 0.f};
      ((float4*)zbuf)[t] = z;
    }
    const int mat = bx >> 11, blk = bx & 2047;
    const float* s = pa.asrc[mat];
    half_t* d = pa.adst[mat];
    size_t i = ((size_t)blk * 256 + t) * 8;
    float4 v0 = *(const float4*)(s + i), v1 = *(const float4*)(s + i + 4);
    f16x8 h;
    h[0]=(half_t)v0.x; h[1]=(half_t)v0.y; h[2]=(half_t)v0.z; h[3]=(half_t)v0.w;
    h[4]=(half_t)v1.x; h[5]=(half_t)v1.y; h[6]=(half_t)v1.z; h[7]=(half_t)v1.w;
    *(f16x8*)(d + i) = h;
  } else {
    const int idx = bx - 8192;          // 0..1279
    const int z = idx >> 8, rem = idx & 255;
    const int k0 = (rem & 15) * 64, n0 = (rem >> 4) * 64;
    const float* W = pa.wsrc[z];
    half_t* D = pa.wdst[z];
#pragma unroll
    for (int it = 0; it < 4; ++it) {
      int id2 = t + it * 256; int r = id2 >> 4, c4 = (id2 & 15) * 4;
      float4 v = *(const float4*)(W + (size_t)(k0 + r) * DM + n0 + c4);
      T[r][c4] = v.x; T[r][c4 + 1] = v.y; T[r][c4 + 2] = v.z; T[r][c4 + 3] = v.w;
    }
    __syncthreads();
#pragma unroll
    for (int it = 0; it < 2; ++it) {
      int id2 = t + it * 256; int n = id2 >> 3, kc = (id2 & 7) * 8;
      f16x8 o;
#pragma unroll
      for (int e = 0; e < 8; ++e) o[e] = (half_t)T[kc + e][n];
      *(f16x8*)&D[(size_t)(n0 + n) * DM + k0 + kc] = o;
    }
  }
}

// =====================================================================
// GEMM: C[M,1024] = A[M,1024](f16) @ Wt[n][k]^T ; z-indexed operand sets.
// Grid must be (8, 32, gz). XCD swizzle: each (z,m0) group's 8 n-blocks
// land on ONE XCD (kept: R10 FETCH evidence, 135 MB vs 42 ideal).
// =====================================================================
struct GArgs {
  const half_t* A[4];  const half_t* Bt[4];
  const float* ba[4]; const float* bu[4]; const float* bv[4];
  half_t* oa[4]; half_t* ob[4]; float* of[4];
};

template<bool F32OUT>
__global__ __launch_bounds__(256) void gemm_k(GArgs g, int K) {
  __shared__ __align__(16) half_t At[128 * 64];
  __shared__ __align__(16) half_t Bt[128 * 64];
  // --- XCD-aware decode (bijective; nwg = 8*32*gz, divisible by 64) ---
  const int lin = blockIdx.x + 8 * (blockIdx.y + 32 * blockIdx.z);
  const int nwg = 8 * 32 * gridDim.z;
  const int xcd = lin & 7, tt = lin >> 3;
  const int grpid = xcd * (nwg >> 6) + (tt >> 3);  // (z,m0) group
  const int n0 = (tt & 7) * 128;
  const int z = grpid >> 5;
  const int m0 = (grpid & 31) * 128;

  const half_t* A = g.A[z];
  const half_t* B = g.Bt[z];
  const int t = threadIdx.x, w = t >> 6, lane = t & 63;
  const f32x4 zf = {0.f, 0.f, 0.f, 0.f};
  f32x4 acc[2][8];
#pragma unroll
  for (int i = 0; i < 2; ++i)
#pragma unroll
    for (int j = 0; j < 8; ++j) acc[i][j] = zf;

  for (int k0 = 0; k0 < K; k0 += 64) {
    stage_gll(At, A + (size_t)m0 * K + k0, K);
    stage_gll(Bt, B + (size_t)n0 * K + k0, K);
    __syncthreads();
    mfma_block(At, Bt, w, lane, acc);
    __syncthreads();
  }
  const int grp = lane >> 4, li = lane & 15;
#pragma unroll
  for (int fr = 0; fr < 2; ++fr)
#pragma unroll
    for (int fc = 0; fc < 8; ++fc)
#pragma unroll
      for (int r = 0; r < 4; ++r) {
        int row = m0 + w * 32 + fr * 16 + grp * 4 + r;
        int col = n0 + fc * 16 + li;
        float v = acc[fr][fc][r];
        if (g.ba[z]) v += g.ba[z][col];
        if constexpr (F32OUT) {
          g.of[z][(size_t)row * DM + col] = v;
        } else {
          float v1 = v + (g.bu[z] ? g.bu[z][col] : 0.f);
          g.oa[z][(size_t)row * DM + col] = (half_t)v1;
          if (g.ob[z]) g.ob[z][(size_t)row * DM + col] = (half_t)(v + g.bv[z][col]);
        }
      }
}

// =====================================================================
// V transpose per head: vp[b*S+s][h*64+d] -> vT[bh][d][s]  (f16)
// =====================================================================
__global__ __launch_bounds__(256) void vtrans(const half_t* vp, half_t* vT) {
  __shared__ half_t T[64][72];
  const int s0 = blockIdx.x * 64, h = blockIdx.y, b = blockIdx.z;
  const int t = threadIdx.x;
#pragma unroll
  for (int it = 0; it < 2; ++it) {
    int idx = t + it * 256; int s = idx >> 3, c = idx & 7;
    uint4 v = *(const uint4*)(vp + ((size_t)(b * S_LEN + s0 + s)) * DM + h * DH + c * 8);
    *(uint4*)&T[s][c * 8] = v;
  }
  __syncthreads();
  half_t* dst = vT + ((size_t)(b * NH + h)) * DH * S_LEN;
#pragma unroll
  for (int it = 0; it < 2; ++it) {
    int idx = t + it * 256; int d = idx >> 3, sc = (idx & 7) * 8;
    f16x8 o;
#pragma unroll
    for (int e = 0; e < 8; ++e) o[e] = T[sc + e][d];
    *(f16x8*)&dst[(size_t)d * S_LEN + s0 + sc] = o;
  }
}

// =====================================================================
// FUSED scores v3: natural grid; writer-side shear with strength-reduced
// addressing: addr(rM) = rM*133 + C, valid window [lo,hi].
// Combine loop: hoisted per-row bases. LDS 50,176 B -> 3 blocks/CU.
// =====================================================================
template<typename ST>
__global__ __launch_bounds__(512, 6) void score_fused(
    const half_t* __restrict__ qu_, const half_t* __restrict__ qv_,
    const half_t* __restrict__ kp_, const half_t* __restrict__ pp_,
    const half_t* __restrict__ zbuf, ST* __restrict__ sc, float* __restrict__ part)
{
  __shared__ __align__(16) half_t MsR[16896];   // 33,792 B
  __shared__ __align__(16) half_t QV[128 * 64]; // 16 KB
  half_t* QU = MsR;                             // phase 1
  half_t* Kt = MsR + 8192;
  half_t* Ms = MsR;                             // phase 2: [128][132] f16

  const int bh = blockIdx.z, b = bh >> 4, h = bh & 15;
  const int kt = blockIdx.x, qt = blockIdx.y;
  const int i0 = qt * 128, k0 = kt * 128;
  const int base = 1920 + k0 - i0;              // in [0,3840]
  const int t = threadIdx.x, w = t >> 6, lane = t & 63;
  const int grp = lane >> 4, li = lane & 15;

  // ---- stage QU, Kt, QV (128x64 each; swizzled global src) ----
  {
    const half_t* srcA = qu_ + ((size_t)(b * S_LEN + i0)) * DM + h * DH;
    const half_t* srcB = kp_ + ((size_t)(b * S_LEN + k0)) * DM + h * DH;
    const half_t* srcQ = qv_ + ((size_t)(b * S_LEN + i0)) * DM + h * DH;
#pragma unroll
    for (int p = 0; p < 2; ++p) {
      int cidx = t + p * 512; int r = cidx >> 3, c = cidx & 7;
      size_t off = (size_t)r * DM + ((c ^ (r & 7)) << 3);
      gll16(srcA + off, QU + (size_t)cidx * 8);
      gll16(srcB + off, Kt + (size_t)cidx * 8);
      gll16(srcQ + off, QV + (size_t)cidx * 8);
    }
  }

  // ---- band B-fragments: global -> registers (rows jv(e), zero row) ----
  const int e0 = w * 16 + li, e1 = (w + 8) * 16 + li;
  const int dlt0 = (base + e0 >= S_LEN + 1) ? 1 : 0;
  const int dlt1 = (base + e1 >= S_LEN + 1) ? 1 : 0;
  f16x8 bm[2][2];
#pragma unroll
  for (int eci = 0; eci < 2; ++eci) {
    int e_row = eci ? e1 : e0;
    int jv = base + e_row; if (jv >= S_LEN + 1) jv -= (S_LEN + 1);
    const half_t* srcp = (jv == S_LEN) ? zbuf
        : pp_ + ((size_t)(b * S_LEN + jv)) * DM + h * DH;
#pragma unroll
    for (int kk = 0; kk < 2; ++kk)
      bm[kk][eci] = *(const f16x8*)(srcp + (kk * 4 + grp) * 8);
  }
  __syncthreads();

  // ---- content MFMA: wave w owns q rows [w*16, w*16+16) ----
  const f32x4 zf = {0.f, 0.f, 0.f, 0.f};
  f32x4 acc_c[8];
#pragma unroll
  for (int j = 0; j < 8; ++j) acc_c[j] = zf;
#pragma unroll
  for (int kk = 0; kk < 2; ++kk) {
    const int chunk = kk * 4 + grp;
    int ra = w * 16 + li;
    f16x8 a = *(const f16x8*)&QU[(size_t)(ra * 8 + (chunk ^ (ra & 7))) * 8];
#pragma unroll
    for (int fc = 0; fc < 8; ++fc) {
      int rb = fc * 16 + li;
      f16x8 bf = *(const f16x8*)&Kt[(size_t)(rb * 8 + (chunk ^ (rb & 7))) * 8];
      acc_c[fc] = __builtin_amdgcn_mfma_f32_16x16x32_f16(a, bf, acc_c[fc], 0, 0, 0);
    }
  }
  __syncthreads();   // QU/Kt reads done; region now writable as Ms

  // ---- band MFMA rf=0..7, writer-side shear (strength-reduced) ----
  const int C0 = e0 - 127 - 133 * dlt0;
  const int C1 = e1 - 127 - 133 * dlt1;
  int lo0 = 127 + dlt0 - e0; if (lo0 < dlt0) lo0 = dlt0;
  int hi0 = 254 + dlt0 - e0; if (hi0 > 127) hi0 = 127;
  int lo1 = 127 + dlt1 - e1; if (lo1 < dlt1) lo1 = dlt1;
  int hi1 = 254 + dlt1 - e1; if (hi1 > 127) hi1 = 127;

  for (int rf = 0; rf < 8; ++rf) {
    f32x4 am[2] = {zf, zf};
#pragma unroll
    for (int kk = 0; kk < 2; ++kk) {
      int ra = rf * 16 + li;
      f16x8 a = *(const f16x8*)&QV[(size_t)(ra * 8 + ((kk * 4 + grp) ^ (ra & 7))) * 8];
      am[0] = __builtin_amdgcn_mfma_f32_16x16x32_f16(a, bm[kk][0], am[0], 0, 0, 0);
      am[1] = __builtin_amdgcn_mfma_f32_16x16x32_f16(a, bm[kk][1], am[1], 0, 0, 0);
    }
    const int rMb = rf * 16 + grp * 4;
    {
      int addr = rMb * 133 + C0;
#pragma unroll
      for (int r = 0; r < 4; ++r) {
        int rM = rMb + r;
        if (rM >= lo0 && rM <= hi0) Ms[addr + 133 * r] = (half_t)am[0][r];
      }
    }
    {
      int addr = rMb * 133 + C1;
#pragma unroll
      for (int r = 0; r < 4; ++r) {
        int rM = rMb + r;
        if (rM >= lo1 && rM <= hi1) Ms[addr + 133 * r] = (half_t)am[1][r];
      }
    }
  }

  // ---- 9th row-frag (rM=128 -> q=127, needs dlt(e)==1, e<128) ----
  {
    f16x8 aq0, aq1;                              // lazy load: short live range
    {
      int r128 = i0 + 128; if (r128 > S_LEN - 1) r128 = S_LEN - 1;
      const half_t* q128p = qv_ + ((size_t)(b * S_LEN + r128)) * DM + h * DH;
      aq0 = *(const f16x8*)(q128p + (0 * 4 + grp) * 8);
      aq1 = *(const f16x8*)(q128p + (1 * 4 + grp) * 8);
    }
    f32x4 am0 = zf;
    am0 = __builtin_amdgcn_mfma_f32_16x16x32_f16(aq0, bm[0][0], am0, 0, 0, 0);
    am0 = __builtin_amdgcn_mfma_f32_16x16x32_f16(aq1, bm[1][0], am0, 0, 0, 0);
    if (grp == 0 && dlt0 == 1)                   // e0 < 128 always (w<8)
      Ms[127 * 132 + e0] = (half_t)am0[0];
  }
  __syncthreads();

  // ---- combine: hoisted bases; s=(content+Ms)/32; exp; write; partials ----
  ST* sb = sc + (size_t)bh * S2;
  const int qb = w * 16 + grp * 4;
  const half_t* MsB = Ms + qb * 132 + li;
  ST* sbB = sb + (size_t)(i0 + qb) * S_LEN + k0 + li;
  float lsum[4];
#pragma unroll
  for (int rr = 0; rr < 4; ++rr) {
    const half_t* mrow = MsB + rr * 132;
    ST* srow = sbB + (size_t)rr * S_LEN;
    float acc = 0.f;
#pragma unroll
    for (int fc = 0; fc < 8; ++fc) {
      float mval = (float)mrow[fc * 16];
      float s = (acc_c[fc][rr] + mval) * 0.03125f;
      float ev = __expf(s);
      srow[fc * 16] = (ST)ev;
      acc += ev;
    }
    lsum[rr] = acc;
  }
#pragma unroll
  for (int rr = 0; rr < 4; ++rr) {
    float v = lsum[rr];
#pragma unroll
    for (int d = 1; d < 16; d <<= 1) v += __shfl_xor(v, d);
    if (li == 0)
      part[((size_t)bh * S_LEN + i0 + qb + rr) * 16 + kt] = v;
  }
}

// =====================================================================
// Pass 3a: PV GEMM ONLY (no attn stores in the loop -> vmcnt waits are
// true load waits; R16/R17 showed the 537MB store stream serialized the
// MFMA pipe via the shared vmcnt queue). A-fragments are the raw f16 exp
// values straight from scH (no convert); PV accumulates UNNORMALIZED and
// the 1/L row scale is applied once in the ctx epilogue.
// V staging double-buffered (proven R14 structure).
// =====================================================================
template<typename ST>
__global__ __launch_bounds__(256) void av_pv(const ST* sc, const half_t* vT, const float* part,
                                             half_t* ctx) {
  __shared__ __align__(16) half_t Vt[2][64 * 128];
  __shared__ float Ls[128];
  const int bh = blockIdx.y, b = bh >> 4, h = bh & 15;
  const int q0 = blockIdx.x * 128;
  const int t = threadIdx.x;
  if (t < 128) {
    const float* pp = part + ((size_t)bh * S_LEN + q0 + t) * 16;
    float L = 0.f;
#pragma unroll
    for (int k = 0; k < 16; ++k) L += pp[k];
    Ls[t] = 1.f / L;
  }
  const ST* sb = sc + (size_t)bh * S2;
  const half_t* vb = vT + (size_t)bh * (DH * S_LEN);
  const int w = t >> 6, lane = t & 63, grp = lane >> 4, li = lane & 15;
  const int c1 = lane & 15, d4 = lane >> 4;
  const f32x4 zf = {0.f, 0.f, 0.f, 0.f};
  f32x4 acc[2][4];
#pragma unroll
  for (int i = 0; i < 2; ++i)
#pragma unroll
    for (int j = 0; j < 4; ++j) acc[i][j] = zf;

  // prologue stage kt=0
#pragma unroll
  for (int it = 0; it < 4; ++it) {
    int d = w * 16 + it * 4 + d4;
    gll16(vb + (size_t)d * S_LEN + ((c1 ^ (d & 15)) << 3), Vt[0] + (size_t)w * 2048 + it * 512);
  }
  __syncthreads();
  int cur = 0;

  for (int kt = 0; kt < 16; ++kt) {
    if (kt + 1 < 16) {
#pragma unroll
      for (int it = 0; it < 4; ++it) {
        int d = w * 16 + it * 4 + d4;
        gll16(vb + (size_t)d * S_LEN + (kt + 1) * 128 + ((c1 ^ (d & 15)) << 3),
              Vt[cur ^ 1] + (size_t)w * 2048 + it * 512);
      }
    }
#pragma unroll
    for (int ks = 0; ks < 4; ++ks) {
      const int col = kt * 128 + ks * 32 + grp * 8;
      f16x8 pa[2];
#pragma unroll
      for (int fr = 0; fr < 2; ++fr) {
        const int row = q0 + w * 32 + fr * 16 + li;
        if constexpr (sizeof(ST) == 2) {
          pa[fr] = *(const f16x8*)&sb[(size_t)row * S_LEN + col];
        } else {
          const f32x4* sp = (const f32x4*)&sb[(size_t)row * S_LEN + col];
          f32x4 a = sp[0], bq = sp[1];
          f16x8 ph;
#pragma unroll
          for (int e = 0; e < 4; ++e) { ph[e] = (half_t)a[e]; ph[4 + e] = (half_t)bq[e]; }
          pa[fr] = ph;
        }
      }
      f16x8 bf[4];
#pragma unroll
      for (int fc = 0; fc < 4; ++fc) {
        int d = fc * 16 + li; int chunk = ks * 4 + grp;
        bf[fc] = *(const f16x8*)&Vt[cur][(size_t)(d * 16 + (chunk ^ (d & 15))) * 8];
      }
#pragma unroll
      for (int fr = 0; fr < 2; ++fr)
#pragma unroll
        for (int fc = 0; fc < 4; ++fc)
          acc[fr][fc] = __builtin_amdgcn_mfma_f32_16x16x32_f16(pa[fr], bf[fc], acc[fr][fc], 0, 0, 0);
    }
    __syncthreads();   // drains V stage of kt+1 (loads only); one barrier/iter
    cur ^= 1;
  }
#pragma unroll
  for (int fr = 0; fr < 2; ++fr)
#pragma unroll
    for (int fc = 0; fc < 4; ++fc)
#pragma unroll
      for (int r = 0; r < 4; ++r) {
        int rq = w * 32 + fr * 16 + grp * 4 + r;
        int q = q0 + rq;
        int d = fc * 16 + li;
        ctx[((size_t)(b * S_LEN + q)) * DM + h * DH + d] = (half_t)(acc[fr][fc][r] * Ls[rq]);
      }
}

// =====================================================================
// Pass 3b: attn = scH * (1/L) -- pure streaming, one row per block.
// (In-place safe for ST=float: attn[i] = attn[i]*rL.)
// =====================================================================
template<typename ST>
__global__ __launch_bounds__(256) void attn_scale(const ST* sc, const float* part,
                                                  float* attn) {
  const size_t row = blockIdx.x;
  const float* pp = part + row * 16;
  float L = 0.f;
#pragma unroll
  for (int k = 0; k < 16; ++k) L += pp[k];
  const float rL = 1.f / L;
  const int t = threadIdx.x;
  float* o = attn + row * S_LEN + t * 8;
  if constexpr (sizeof(ST) == 2) {
    f16x8 v = *(const f16x8*)(sc + row * S_LEN + t * 8);
    f32x4 w0, w1;
#pragma unroll
    for (int e = 0; e < 4; ++e) { w0[e] = (float)v[e] * rL; w1[e] = (float)v[4 + e] * rL; }
    ((f32x4*)o)[0] = w0;
    ((f32x4*)o)[1] = w1;
  } else {
    f32x4* op = (f32x4*)o;
    f32x4 a = op[0], bq = op[1];
#pragma unroll
    for (int e = 0; e < 4; ++e) { a[e] *= rL; bq[e] *= rL; }
    op[0] = a; op[1] = bq;
  }
}

// =====================================================================
extern "C" void kernel_launch(void* const* d_in, const int* in_sizes, int n_in,
                              void* d_out, int out_size, void* d_ws, size_t ws_size,
                              hipStream_t stream) {
  (void)in_sizes; (void)n_in; (void)out_size;

  const float* query  = (const float*)d_in[0];
  const float* key    = (const float*)d_in[1];
  const float* value  = (const float*)d_in[2];
  const float* pos    = (const float*)d_in[3];
  const float* Wq     = (const float*)d_in[4];
  const float* bq     = (const float*)d_in[5];
  const float* Wk     = (const float*)d_in[6];
  const float* bk     = (const float*)d_in[7];
  const float* Wv     = (const float*)d_in[8];
  const float* bv     = (const float*)d_in[9];
  const float* Wpos   = (const float*)d_in[10];
  const float* u_bias = (const float*)d_in[11];  // [16,64] == flat [1024]
  const float* v_bias = (const float*)d_in[12];
  const float* Wout   = (const float*)d_in[13];
  const float* bout   = (const float*)d_in[14];

  float* out  = (float*)d_out;
  float* attn = out + (size_t)BATCH * S_LEN * DM;

  char* ws = (char*)d_ws;
  half_t* Wt   = (half_t*)(ws);                 // 5 x 1024x1024 f16 = 10,485,760 B
  half_t* Af16 = (half_t*)(ws + 10485760);      // 4 x 8,388,608 B (dead after proj)
  float*  part = (float*)(ws + 10485760);       // 4 MB, aliases Af16[0] post-proj
  half_t* qu   = (half_t*)(ws + 44040192);
  half_t* qv   = (half_t*)(ws + 52428800);
  half_t* kp   = (half_t*)(ws + 60817408);
  half_t* pp   = (half_t*)(ws + 69206016);
  half_t* vp   = (half_t*)(ws + 77594624);
  half_t* vT   = (half_t*)(ws + 85983232);
  half_t* ctx  = (half_t*)(ws + 77594624);      // alias vp (dead after vtrans)
  half_t* zbuf = (half_t*)(ws + 94371840);      // 128 B zero row
  half_t* scH  = (half_t*)(ws + 94375936);      // 268,435,456 B if it fits
  const bool fast = ws_size >= (size_t)94375936 + (size_t)BATCH * NH * S2 * 2;

  dim3 blk(256);

  // 0. prep: activations -> f16 + zbuf init + weights -> f16 transposed
  PArgs pa;
  pa.asrc[0] = query; pa.asrc[1] = key; pa.asrc[2] = value; pa.asrc[3] = pos;
  for (int i = 0; i < 4; ++i) pa.adst[i] = Af16 + (size_t)i * CTXSZ;
  pa.wsrc[0] = Wq; pa.wsrc[1] = Wk; pa.wsrc[2] = Wv; pa.wsrc[3] = Wpos; pa.wsrc[4] = Wout;
  for (int i = 0; i < 5; ++i) pa.wdst[i] = Wt + (size_t)i * DM * DM;
  prep<<<dim3(8192 + 1280), blk, 0, stream>>>(pa, zbuf);

  // 1. projections (q dual-output with u/v biases, k, v, p) in one launch
  GArgs ga{};
  for (int i = 0; i < 4; ++i) {
    ga.A[i]  = Af16 + (size_t)i * CTXSZ;
    ga.Bt[i] = Wt + (size_t)i * DM * DM;
  }
  ga.ba[0] = bq; ga.ba[1] = bk; ga.ba[2] = bv; ga.ba[3] = nullptr;
  ga.bu[0] = u_bias; ga.bv[0] = v_bias;
  ga.oa[0] = qu; ga.oa[1] = kp; ga.oa[2] = vp; ga.oa[3] = pp;
  ga.ob[0] = qv;
  gemm_k<false><<<dim3(8, 32, 4), blk, 0, stream>>>(ga, DM);

  // 2. V -> per-head transposed [bh][d][s]
  vtrans<<<dim3(32, 16, 2), blk, 0, stream>>>(vp, vT);

  // 3. fused scores; 4a. PV (load-only loop); 4b. attn scale (streaming)
  dim3 g_sc(16, 16, 32);
  dim3 blk5(512);
  const int nrows = BATCH * NH * S_LEN;
  if (fast) {
    score_fused<half_t><<<g_sc, blk5, 0, stream>>>(qu, qv, kp, pp, zbuf, scH, part);
    av_pv<half_t><<<dim3(16, 32), blk, 0, stream>>>(scH, vT, part, ctx);
    attn_scale<half_t><<<dim3(nrows), blk, 0, stream>>>(scH, part, attn);
  } else {
    float* scF = attn;  // f32 exp-scores in-place in the attn output region
    score_fused<float><<<g_sc, blk5, 0, stream>>>(qu, qv, kp, pp, zbuf, scF, part);
    av_pv<float><<<dim3(16, 32), blk, 0, stream>>>(scF, vT, part, ctx);
    attn_scale<float><<<dim3(nrows), blk, 0, stream>>>(scF, part, attn);
  }

  // 5. out = ctx @ Wout^T + bout  (f32 output)
  GArgs go{};
  go.A[0] = ctx; go.Bt[0] = Wt + (size_t)4 * DM * DM;
  go.ba[0] = bout; go.of[0] = out;
  gemm_k<true><<<dim3(8, 32, 1), blk, 0, stream>>>(go, DM);
}